// Round 18
// baseline (233.603 us; speedup 1.0000x reference)
//
#include <hip/hip_runtime.h>
#include <math.h>

#define N 16384
#define D 1024
#define EPSF 1e-8f
#define QSCALE 448.0f
#define NPAIRS 2080
#define NBLK 256
#define PANB 262144 /* bytes per 256-row i8 panel */
#define BIAS 16777216u

typedef __attribute__((ext_vector_type(4))) int i32x4;
typedef unsigned int u32;
typedef unsigned long long u64;

// LDS: A ring4 [0,64K), B ring4 [64K,128K), s_next [128K,+16)
#define LDS_Bb 65536
#define LDS_TOT 131088

__device__ __forceinline__ void gload_lds16(const void* g, void* l) {
  __builtin_amdgcn_global_load_lds(
      (const __attribute__((address_space(1))) u32*)g,
      (__attribute__((address_space(3))) u32*)l, 16, 0, 0);
}

__device__ __forceinline__ int maxi(int x, int y) { return x > y ? x : y; }
__device__ __forceinline__ u32 maxu(u32 x, u32 y) { return x > y ? x : y; }

__device__ __forceinline__ void decode_pair(int t, int& a, int& b) {
  int aa = (int)((129.0 - sqrt(129.0 * 129.0 - 8.0 * (double)t)) * 0.5);
  if (aa < 0) aa = 0;
  if (aa > 63) aa = 63;
  while (((aa + 1) * 64 - ((aa + 1) * aa) / 2) <= t) ++aa;
  while ((aa * 64 - (aa * (aa - 1)) / 2) > t) --aa;
  a = aa;
  b = aa + (t - (aa * 64 - (aa * (aa - 1)) / 2));
}

// ---------- kernel 1: norms + globally-scaled i8 matrix + zero best/ctr ----------

__global__ __launch_bounds__(256) void k_normalize(
    const float* __restrict__ x, signed char* __restrict__ xq,
    float* __restrict__ norms, u64* __restrict__ best, int* __restrict__ ctr) {
  const int w = threadIdx.x >> 6, lane = threadIdx.x & 63;
  const int i = blockIdx.x * 4 + w;  // one wave per row
  if (threadIdx.x < 4) best[(size_t)blockIdx.x * 4 + threadIdx.x] = 0;
  if (blockIdx.x == 0 && threadIdx.x == 0) *ctr = 0;
  const float4* xi = (const float4*)(x + (size_t)i * D);
  float4 v[4];
  float s = 0.f;
#pragma unroll
  for (int t = 0; t < 4; ++t) {
    v[t] = xi[lane + t * 64];
    s += v[t].x * v[t].x + v[t].y * v[t].y + v[t].z * v[t].z + v[t].w * v[t].w;
  }
#pragma unroll
  for (int sh = 32; sh; sh >>= 1) s += __shfl_xor(s, sh, 64);
  const float nrm = sqrtf(s);
  if (lane == 0) norms[i] = nrm;
  const float qs = QSCALE / fmaxf(nrm, EPSF);
  u32* xo = (u32*)(xq + (size_t)i * D);
#pragma unroll
  for (int t = 0; t < 4; ++t) {
    const int q0 = __float2int_rn(fminf(fmaxf(v[t].x * qs, -127.f), 127.f));
    const int q1 = __float2int_rn(fminf(fmaxf(v[t].y * qs, -127.f), 127.f));
    const int q2 = __float2int_rn(fminf(fmaxf(v[t].z * qs, -127.f), 127.f));
    const int q3 = __float2int_rn(fminf(fmaxf(v[t].w * qs, -127.f), 127.f));
    xo[lane + t * 64] = (u32)(q0 & 0xff) | ((u32)(q1 & 0xff) << 8) |
                        ((u32)(q2 & 0xff) << 16) | ((u32)(q3 & 0xff) << 24);
  }
}

// ---------- kernel 2: work-stealing symmetric-pair i8 MFMA argmax (R12 body) ----------
// 256 blocks (1/CU), 512 thr = 8 waves (4M x 2N), per-wave C = 64x128.
// Pairs stolen one-ahead via global atomicAdd + LDS parity slots (published
// by the in-loop barriers; R9 protocol). Rolled kq loop, 4 compile-time-slot
// KTs/iter, ring-4 LDS (swizzled), stage 3 ahead rolling into the stolen
// next pair, 1 barrier + counted vmcnt(8) per K-tile. Unsigned packed
// epilogue; deterministic u64 atomicMax publish (order-independent).

#define SGB(gaddr, daddr) \
  gload_lds16(xqB + (gaddr) + srcLane, lds + (daddr) + w * 1024)

#define KT(C_)                                                                 \
  {                                                                            \
    const int k_ = kq * 4 + (C_);                                              \
    const int t_ = k_ + 3;                                                     \
    const int kt_ = t_ & 15;                                                   \
    const size_t aG = (t_ >= 16 ? aPanN : aPan) + (size_t)(kt_ * 64);          \
    const size_t bG = (t_ >= 16 ? bPanN : bPan) + (size_t)(kt_ * 64);          \
    __builtin_amdgcn_s_barrier();                                              \
    asm volatile("" ::: "memory");                                             \
    SGB(aG, (((C_) + 3) & 3) * 16384);                                         \
    SGB(aG + 131072, (((C_) + 3) & 3) * 16384 + 8192);                         \
    SGB(bG, LDS_Bb + (((C_) + 3) & 3) * 16384);                                \
    SGB(bG + 131072, LDS_Bb + (((C_) + 3) & 3) * 16384 + 8192);                \
    i32x4 aa[4], bb[4];                                                        \
    _Pragma("unroll") for (int m = 0; m < 4; ++m) aa[m] =                      \
        *(const i32x4*)(lds + ((C_)&3) * 16384 + aOff[m]);                     \
    _Pragma("unroll") for (int n = 0; n < 4; ++n) bb[n] =                      \
        *(const i32x4*)(lds + LDS_Bb + ((C_)&3) * 16384 + bOff[n]);            \
    __builtin_amdgcn_s_setprio(1);                                             \
    _Pragma("unroll") for (int m = 0; m < 4; ++m)                              \
      _Pragma("unroll") for (int n = 0; n < 4; ++n)                            \
        acc[m][n] = __builtin_amdgcn_mfma_i32_16x16x64_i8(aa[m], bb[n],        \
                                                          acc[m][n], 0, 0, 0); \
    __builtin_amdgcn_s_setprio(0);                                             \
    _Pragma("unroll") for (int n = 0; n < 4; ++n) bb[n] =                      \
        *(const i32x4*)(lds + LDS_Bb + ((C_)&3) * 16384 + bOff[4 + n]);        \
    __builtin_amdgcn_s_setprio(1);                                             \
    _Pragma("unroll") for (int m = 0; m < 4; ++m)                              \
      _Pragma("unroll") for (int n = 0; n < 4; ++n)                            \
        acc[m][4 + n] = __builtin_amdgcn_mfma_i32_16x16x64_i8(                 \
            aa[m], bb[n], acc[m][4 + n], 0, 0, 0);                             \
    __builtin_amdgcn_s_setprio(0);                                             \
    asm volatile("s_waitcnt vmcnt(8)" ::: "memory");                           \
  }

__global__ __launch_bounds__(512, 2) void k_argmax(
    const signed char* __restrict__ xq, u64* __restrict__ best,
    int* __restrict__ ctr) {
  extern __shared__ char lds[];
  int* s_next = (int*)(lds + 131072);  // 2 parity slots
  const char* xqB = (const char*)xq;
  const int tid = (int)threadIdx.x, lane = tid & 63, w = tid >> 6;
  const int wr = w >> 1, wc = w & 1;

  // LDS slot (16KB): 256 rows x 64B, 2 rows/128B line,
  // granule swizzle: inner = (((rr&1)<<6)|(q<<4)) ^ ((line&7)<<4)
  int aOff[4], bOff[8];
  const int q = lane >> 4, li = lane & 15;
#pragma unroll
  for (int m = 0; m < 4; ++m) {
    const int rr = wr * 64 + m * 16 + li;
    const int line = rr >> 1;
    aOff[m] = line * 128 + ((((rr & 1) << 6) | (q << 4)) ^ ((line & 7) << 4));
  }
#pragma unroll
  for (int nf = 0; nf < 8; ++nf) {
    const int rr = wc * 128 + nf * 16 + li;
    const int line = rr >> 1;
    bOff[nf] = line * 128 + ((((rr & 1) << 6) | (q << 4)) ^ ((line & 7) << 4));
  }
  // staging per-lane source offset (inverse swizzle; linear gload dest)
  const int posx = (lane & 7) ^ (lane >> 3);
  const int rrl = ((w * 8 + (lane >> 3)) << 1) | (posx >> 2);
  const int srcLane = rrl * 1024 + (posx & 3) * 16;

  const int rB2 = wr * 64 + (q << 2);
  const int cB2 = wc * 128 + li;

  // bootstrap: steal first two pairs
  if (tid == 0) {
    s_next[0] = atomicAdd(ctr, 1);
    s_next[1] = atomicAdd(ctr, 1);
  }
  __syncthreads();
  int pcur = s_next[0], pnext = s_next[1];
  __syncthreads();
  if (pcur >= NPAIRS) return;

  int a, b;
  decode_pair(pcur, a, b);
  size_t aPan = (size_t)a * PANB, bPan = (size_t)b * PANB;

  // prologue: stage K-tiles 0..2 into ring slots 0..2
  for (int pp = 0; pp < 3; ++pp) {
    SGB(aPan + (size_t)(pp * 64), pp * 16384);
    SGB(aPan + (size_t)(pp * 64) + 131072, pp * 16384 + 8192);
    SGB(bPan + (size_t)(pp * 64), LDS_Bb + pp * 16384);
    SGB(bPan + (size_t)(pp * 64) + 131072, LDS_Bb + pp * 16384 + 8192);
  }
  asm volatile("s_waitcnt vmcnt(8)" ::: "memory");

  int par = 0;
  i32x4 acc[4][8];
  while (true) {
    const bool hasNext = (pnext < NPAIRS);
    int an = a, bn = b;
    if (hasNext) decode_pair(pnext, an, bn);
    const size_t aPanN = (size_t)an * PANB, bPanN = (size_t)bn * PANB;
    if (tid == 0) s_next[par] = atomicAdd(ctr, 1);  // steal pair-after-next

#pragma unroll
    for (int m = 0; m < 4; ++m)
#pragma unroll
      for (int n = 0; n < 8; ++n) acc[m][n] = (i32x4){0, 0, 0, 0};

    for (int kq = 0; kq < 4; ++kq) {
      KT(0)
      KT(1)
      KT(2)
      KT(3)
    }

    // ---- epilogue: packed folds, u64 atomicMax publish ----
    const int aBase = a * 256, colBase = b * 256;
    // row-side: u32 pack ((dot+2^24)<<7)|(nf<<4|li), UNSIGNED fold
    // (max 33.3e6*128 = 4.26e9 < 2^32, monotone in dot)
#pragma unroll
    for (int m = 0; m < 4; ++m)
#pragma unroll
      for (int r = 0; r < 4; ++r) {
        const int rl = rB2 + m * 16 + r;
        u32 pk = 0;
        if (a == b) {
#pragma unroll
          for (int nf = 0; nf < 8; ++nf) {
            u32 v = (((u32)acc[m][nf][r] + BIAS) << 7) | (u32)((nf << 4) | li);
            if (rl == cB2 + nf * 16) v = 0;
            pk = maxu(pk, v);
          }
        } else {
#pragma unroll
          for (int nf = 0; nf < 8; ++nf) {
            const u32 v =
                (((u32)acc[m][nf][r] + BIAS) << 7) | (u32)((nf << 4) | li);
            pk = maxu(pk, v);
          }
        }
#pragma unroll
        for (int sh = 1; sh < 16; sh <<= 1)
          pk = maxu(pk, (u32)__shfl_xor((int)pk, sh, 64));
        if (li == 0) {
          const int dot = (int)(pk >> 7) - (int)BIAS;
          const int col = colBase + wc * 128 + (int)(pk & 127u);
          const u64 key = ((u64)((u32)dot ^ 0x80000000u) << 32) | (u32)col;
          atomicMax(best + (aBase + rl), key);
        }
      }

    // col-side: rows of b, candidates = rows of a (skip on diagonal).
    // pack ((dot+2^24)<<6)|idx6: max 2.131e9 < 2^31-1, signed fold OK
    if (a != b) {
#pragma unroll
      for (int nf = 0; nf < 8; ++nf) {
        int pk = 0;
#pragma unroll
        for (int m = 0; m < 4; ++m)
#pragma unroll
          for (int r = 0; r < 4; ++r) {
            const int v = (int)((((u32)acc[m][nf][r] + BIAS) << 6) |
                                (u32)(m * 16 + q * 4 + r));
            pk = maxi(pk, v);
          }
        pk = maxi(pk, __shfl_xor(pk, 16, 64));
        pk = maxi(pk, __shfl_xor(pk, 32, 64));
        if (q == 0) {
          const int dot = (int)((((u32)pk) >> 6) - BIAS);
          const int grow = aBase + wr * 64 + (pk & 63);
          const u64 key = ((u64)((u32)dot ^ 0x80000000u) << 32) | (u32)grow;
          atomicMax(best + (colBase + cB2 + nf * 16), key);
        }
      }
    }

    if (!hasNext) break;
    const int pnn = s_next[par];  // published by the 16 KT barriers
    pcur = pnext;
    a = an;
    b = bn;
    aPan = aPanN;
    bPan = bPanN;
    pnext = pnn;
    par ^= 1;
  }
}

// ---------- kernel 3: exact fp32 distance + log ----------

__global__ __launch_bounds__(256) void k_dist(
    const float* __restrict__ x, const float* __restrict__ norms,
    const u64* __restrict__ best, float* __restrict__ logd) {
  const int w = threadIdx.x >> 6, lane = threadIdx.x & 63;
  const int i = blockIdx.x * 4 + w;
  const u64 p = best[i];
  const int j = (int)(p & 0xffffffffu);
  const float invi = 1.f / fmaxf(norms[i], EPSF);
  const float invj = 1.f / fmaxf(norms[j], EPSF);
  const float4* xi = (const float4*)(x + (size_t)i * D);
  const float4* xj = (const float4*)(x + (size_t)j * D);
  float s = 0.f;
#pragma unroll
  for (int t = 0; t < 4; ++t) {
    const float4 av = xi[lane + t * 64], bv = xj[lane + t * 64];
    float d;
    d = av.x * invi - bv.x * invj + EPSF; s += d * d;
    d = av.y * invi - bv.y * invj + EPSF; s += d * d;
    d = av.z * invi - bv.z * invj + EPSF; s += d * d;
    d = av.w * invi - bv.w * invj + EPSF; s += d * d;
  }
#pragma unroll
  for (int sh = 32; sh; sh >>= 1) s += __shfl_xor(s, sh, 64);
  if (lane == 0) logd[i] = logf(sqrtf(s) + EPSF);
}

// ---------- kernel 4: deterministic fixed-order mean ----------

__global__ __launch_bounds__(256) void k_final(const float* __restrict__ logd,
                                               float* __restrict__ out) {
  __shared__ double red[256];
  double s = 0.0;
  for (int i = threadIdx.x; i < N; i += 256) s += (double)logd[i];
  red[threadIdx.x] = s;
  __syncthreads();
  for (int sh = 128; sh; sh >>= 1) {
    if ((int)threadIdx.x < sh) red[threadIdx.x] += red[threadIdx.x + sh];
    __syncthreads();
  }
  if (threadIdx.x == 0) out[0] = (float)(-red[0] / (double)N);
}

// ---------- launch ----------

extern "C" void kernel_launch(void* const* d_in, const int* in_sizes, int n_in,
                              void* d_out, int out_size, void* d_ws,
                              size_t ws_size, hipStream_t stream) {
  const float* x = (const float*)d_in[0];
  float* out = (float*)d_out;
  char* ws = (char*)d_ws;

  // ws: xq 16MB | norms 64KB | best N*8 = 128KB | logd 64KB | ctr 64B
  signed char* xq = (signed char*)ws;
  float* norms = (float*)(ws + 16777216);
  u64* best = (u64*)(ws + 16842752);
  float* logd = (float*)(ws + 16973824);
  int* ctr = (int*)(ws + 17039360);

  k_normalize<<<N / 4, 256, 0, stream>>>(x, xq, norms, best, ctr);
  k_argmax<<<NBLK, 512, LDS_TOT, stream>>>(xq, best, ctr);
  k_dist<<<N / 4, 256, 0, stream>>>(x, norms, best, logd);
  k_final<<<1, 256, 0, stream>>>(logd, out);
}

// Round 19
// 218.515 us; speedup vs baseline: 1.0690x; 1.0690x over previous
//
#include <hip/hip_runtime.h>
#include <math.h>

#define N 16384
#define D 1024
#define EPSF 1e-8f
#define QSCALE 448.0f
#define NPAIRS 2080
#define NBLK 256
#define PANB 262144 /* bytes per 256-row i8 panel */
#define BIAS 16777216u

typedef __attribute__((ext_vector_type(4))) int i32x4;
typedef unsigned int u32;
typedef unsigned long long u64;

// LDS: A ring4 [0,64K), B ring4 [64K,128K)
#define LDS_Bb 65536
#define LDS_TOT 131072

__device__ __forceinline__ void gload_lds16(const void* g, void* l) {
  __builtin_amdgcn_global_load_lds(
      (const __attribute__((address_space(1))) u32*)g,
      (__attribute__((address_space(3))) u32*)l, 16, 0, 0);
}

__device__ __forceinline__ int maxi(int x, int y) { return x > y ? x : y; }
__device__ __forceinline__ u32 maxu(u32 x, u32 y) { return x > y ? x : y; }

__device__ __forceinline__ void decode_pair(int t, int& a, int& b) {
  int aa = (int)((129.0 - sqrt(129.0 * 129.0 - 8.0 * (double)t)) * 0.5);
  if (aa < 0) aa = 0;
  if (aa > 63) aa = 63;
  while (((aa + 1) * 64 - ((aa + 1) * aa) / 2) <= t) ++aa;
  while ((aa * 64 - (aa * (aa - 1)) / 2) > t) --aa;
  a = aa;
  b = aa + (t - (aa * 64 - (aa * (aa - 1)) / 2));
}

// ---------- kernel 1: norms + globally-scaled i8 matrix + zero best ----------

__global__ __launch_bounds__(256) void k_normalize(
    const float* __restrict__ x, signed char* __restrict__ xq,
    float* __restrict__ norms, u64* __restrict__ best) {
  const int w = threadIdx.x >> 6, lane = threadIdx.x & 63;
  const int i = blockIdx.x * 4 + w;  // one wave per row
  if (threadIdx.x < 4) best[(size_t)blockIdx.x * 4 + threadIdx.x] = 0;
  const float4* xi = (const float4*)(x + (size_t)i * D);
  float4 v[4];
  float s = 0.f;
#pragma unroll
  for (int t = 0; t < 4; ++t) {
    v[t] = xi[lane + t * 64];
    s += v[t].x * v[t].x + v[t].y * v[t].y + v[t].z * v[t].z + v[t].w * v[t].w;
  }
#pragma unroll
  for (int sh = 32; sh; sh >>= 1) s += __shfl_xor(s, sh, 64);
  const float nrm = sqrtf(s);
  if (lane == 0) norms[i] = nrm;
  const float qs = QSCALE / fmaxf(nrm, EPSF);
  u32* xo = (u32*)(xq + (size_t)i * D);
#pragma unroll
  for (int t = 0; t < 4; ++t) {
    const int q0 = __float2int_rn(fminf(fmaxf(v[t].x * qs, -127.f), 127.f));
    const int q1 = __float2int_rn(fminf(fmaxf(v[t].y * qs, -127.f), 127.f));
    const int q2 = __float2int_rn(fminf(fmaxf(v[t].z * qs, -127.f), 127.f));
    const int q3 = __float2int_rn(fminf(fmaxf(v[t].w * qs, -127.f), 127.f));
    xo[lane + t * 64] = (u32)(q0 & 0xff) | ((u32)(q1 & 0xff) << 8) |
                        ((u32)(q2 & 0xff) << 16) | ((u32)(q3 & 0xff) << 24);
  }
}

// ---------- kernel 2: chunked symmetric-pair i8 MFMA argmax (R12 body) ----------
// 256 blocks; block c owns pairs [c*2080/256,(c+1)*2080/256) in (a,b)-lex
// order (A-panel L2-hot across the chunk). 512 thr = 8 waves (4M x 2N),
// per-wave C = 64x128. Rolled kq loop, 4 compile-time-slot KTs per iter,
// ring-4 LDS (swizzled), stage 3 tiles ahead rolling into the next pair,
// 1 barrier + counted vmcnt(8) per K-tile. UNSIGNED packed row fold
// (R12's signed fold overflowed -- R13 fix), u64 atomicMax publish.

#define SGB(gaddr, daddr) \
  gload_lds16(xqB + (gaddr) + srcLane, lds + (daddr) + w * 1024)

#define KT(C_)                                                                 \
  {                                                                            \
    const int k_ = kq * 4 + (C_);                                              \
    const int t_ = k_ + 3;                                                     \
    const int kt_ = t_ & 15;                                                   \
    const size_t aG = (t_ >= 16 ? aPanN : aPan) + (size_t)(kt_ * 64);          \
    const size_t bG = (t_ >= 16 ? bPanN : bPan) + (size_t)(kt_ * 64);          \
    __builtin_amdgcn_s_barrier();                                              \
    asm volatile("" ::: "memory");                                             \
    SGB(aG, (((C_) + 3) & 3) * 16384);                                         \
    SGB(aG + 131072, (((C_) + 3) & 3) * 16384 + 8192);                         \
    SGB(bG, LDS_Bb + (((C_) + 3) & 3) * 16384);                                \
    SGB(bG + 131072, LDS_Bb + (((C_) + 3) & 3) * 16384 + 8192);                \
    i32x4 aa[4], bb[4];                                                        \
    _Pragma("unroll") for (int m = 0; m < 4; ++m) aa[m] =                      \
        *(const i32x4*)(lds + ((C_)&3) * 16384 + aOff[m]);                     \
    _Pragma("unroll") for (int n = 0; n < 4; ++n) bb[n] =                      \
        *(const i32x4*)(lds + LDS_Bb + ((C_)&3) * 16384 + bOff[n]);            \
    __builtin_amdgcn_s_setprio(1);                                             \
    _Pragma("unroll") for (int m = 0; m < 4; ++m)                              \
      _Pragma("unroll") for (int n = 0; n < 4; ++n)                            \
        acc[m][n] = __builtin_amdgcn_mfma_i32_16x16x64_i8(aa[m], bb[n],        \
                                                          acc[m][n], 0, 0, 0); \
    __builtin_amdgcn_s_setprio(0);                                             \
    _Pragma("unroll") for (int n = 0; n < 4; ++n) bb[n] =                      \
        *(const i32x4*)(lds + LDS_Bb + ((C_)&3) * 16384 + bOff[4 + n]);        \
    __builtin_amdgcn_s_setprio(1);                                             \
    _Pragma("unroll") for (int m = 0; m < 4; ++m)                              \
      _Pragma("unroll") for (int n = 0; n < 4; ++n)                            \
        acc[m][4 + n] = __builtin_amdgcn_mfma_i32_16x16x64_i8(                 \
            aa[m], bb[n], acc[m][4 + n], 0, 0, 0);                             \
    __builtin_amdgcn_s_setprio(0);                                             \
    asm volatile("s_waitcnt vmcnt(8)" ::: "memory");                           \
  }

__global__ __launch_bounds__(512, 2) void k_argmax(
    const signed char* __restrict__ xq, u64* __restrict__ best) {
  extern __shared__ char lds[];
  const char* xqB = (const char*)xq;
  const int tid = (int)threadIdx.x, lane = tid & 63, w = tid >> 6;
  const int wr = w >> 1, wc = w & 1;

  // LDS slot (16KB): 256 rows x 64B, 2 rows/128B line,
  // granule swizzle: inner = (((rr&1)<<6)|(q<<4)) ^ ((line&7)<<4)
  int aOff[4], bOff[8];
  const int q = lane >> 4, li = lane & 15;
#pragma unroll
  for (int m = 0; m < 4; ++m) {
    const int rr = wr * 64 + m * 16 + li;
    const int line = rr >> 1;
    aOff[m] = line * 128 + ((((rr & 1) << 6) | (q << 4)) ^ ((line & 7) << 4));
  }
#pragma unroll
  for (int nf = 0; nf < 8; ++nf) {
    const int rr = wc * 128 + nf * 16 + li;
    const int line = rr >> 1;
    bOff[nf] = line * 128 + ((((rr & 1) << 6) | (q << 4)) ^ ((line & 7) << 4));
  }
  // staging per-lane source offset (inverse swizzle; linear gload dest)
  const int posx = (lane & 7) ^ (lane >> 3);
  const int rrl = ((w * 8 + (lane >> 3)) << 1) | (posx >> 2);
  const int srcLane = rrl * 1024 + (posx & 3) * 16;

  const int rB2 = wr * 64 + (q << 2);
  const int cB2 = wc * 128 + li;

  // static chunk of the triangle pair list
  const int p0 = ((int)blockIdx.x * NPAIRS) / NBLK;
  const int p1 = (((int)blockIdx.x + 1) * NPAIRS) / NBLK;
  int a, b;
  decode_pair(p0, a, b);
  size_t aPan = (size_t)a * PANB, bPan = (size_t)b * PANB;

  // prologue: stage K-tiles 0..2 into ring slots 0..2
  for (int pp = 0; pp < 3; ++pp) {
    SGB(aPan + (size_t)(pp * 64), pp * 16384);
    SGB(aPan + (size_t)(pp * 64) + 131072, pp * 16384 + 8192);
    SGB(bPan + (size_t)(pp * 64), LDS_Bb + pp * 16384);
    SGB(bPan + (size_t)(pp * 64) + 131072, LDS_Bb + pp * 16384 + 8192);
  }
  asm volatile("s_waitcnt vmcnt(8)" ::: "memory");

  i32x4 acc[4][8];
  for (int p = p0; p < p1; ++p) {
    // next pair (dup-stage own panels on the last pair -- harmless)
    int an = a, bn = b + 1;
    if (bn == 64) {
      an = a + 1;
      bn = an;
    }
    const bool lastp = (p == p1 - 1);
    const size_t aPanN = lastp ? aPan : (size_t)an * PANB;
    const size_t bPanN = lastp ? bPan : (size_t)bn * PANB;

#pragma unroll
    for (int m = 0; m < 4; ++m)
#pragma unroll
      for (int n = 0; n < 8; ++n) acc[m][n] = (i32x4){0, 0, 0, 0};

    for (int kq = 0; kq < 4; ++kq) {
      KT(0)
      KT(1)
      KT(2)
      KT(3)
    }

    // ---- epilogue: packed folds, u64 atomicMax publish ----
    const int aBase = a * 256, colBase = b * 256;
    // row-side: u32 pack ((dot+2^24)<<7)|(nf<<4|li), UNSIGNED fold
    // (max (2^25-1)*128 = 4.29e9 < 2^32, monotone in dot)
#pragma unroll
    for (int m = 0; m < 4; ++m)
#pragma unroll
      for (int r = 0; r < 4; ++r) {
        const int rl = rB2 + m * 16 + r;
        u32 pk = 0;  // sentinel below all valid packs
        if (a == b) {
#pragma unroll
          for (int nf = 0; nf < 8; ++nf) {
            u32 v = (((u32)acc[m][nf][r] + BIAS) << 7) | (u32)((nf << 4) | li);
            if (rl == cB2 + nf * 16) v = 0;
            pk = maxu(pk, v);
          }
        } else {
#pragma unroll
          for (int nf = 0; nf < 8; ++nf) {
            const u32 v =
                (((u32)acc[m][nf][r] + BIAS) << 7) | (u32)((nf << 4) | li);
            pk = maxu(pk, v);
          }
        }
#pragma unroll
        for (int sh = 1; sh < 16; sh <<= 1)
          pk = maxu(pk, (u32)__shfl_xor((int)pk, sh, 64));
        if (li == 0) {
          const int dot = (int)(pk >> 7) - (int)BIAS;
          const int col = colBase + wc * 128 + (int)(pk & 127u);
          const u64 key = ((u64)((u32)dot ^ 0x80000000u) << 32) | (u32)col;
          atomicMax(best + (aBase + rl), key);
        }
      }

    // col-side: rows of b, candidates = rows of a (skip on diagonal).
    // pack ((dot+2^24)<<6)|idx6: max 2.13e9 < 2^31-1, signed fold OK
    if (a != b) {
#pragma unroll
      for (int nf = 0; nf < 8; ++nf) {
        int pk = 0;
#pragma unroll
        for (int m = 0; m < 4; ++m)
#pragma unroll
          for (int r = 0; r < 4; ++r) {
            const int v = (int)((((u32)acc[m][nf][r] + BIAS) << 6) |
                                (u32)(m * 16 + q * 4 + r));
            pk = maxi(pk, v);
          }
        pk = maxi(pk, __shfl_xor(pk, 16, 64));
        pk = maxi(pk, __shfl_xor(pk, 32, 64));
        if (q == 0) {
          const int dot = (int)((((u32)pk) >> 6) - BIAS);
          const int grow = aBase + wr * 64 + (pk & 63);
          const u64 key = ((u64)((u32)dot ^ 0x80000000u) << 32) | (u32)grow;
          atomicMax(best + (colBase + cB2 + nf * 16), key);
        }
      }
    }

    a = an;
    b = bn;
    aPan = (size_t)a * PANB;
    bPan = (size_t)b * PANB;
  }
}

// ---------- kernel 3: exact fp32 distance + log ----------

__global__ __launch_bounds__(256) void k_dist(
    const float* __restrict__ x, const float* __restrict__ norms,
    const u64* __restrict__ best, float* __restrict__ logd) {
  const int w = threadIdx.x >> 6, lane = threadIdx.x & 63;
  const int i = blockIdx.x * 4 + w;
  const u64 p = best[i];
  const int j = (int)(p & 0xffffffffu);
  const float invi = 1.f / fmaxf(norms[i], EPSF);
  const float invj = 1.f / fmaxf(norms[j], EPSF);
  const float4* xi = (const float4*)(x + (size_t)i * D);
  const float4* xj = (const float4*)(x + (size_t)j * D);
  float s = 0.f;
#pragma unroll
  for (int t = 0; t < 4; ++t) {
    const float4 av = xi[lane + t * 64], bv = xj[lane + t * 64];
    float d;
    d = av.x * invi - bv.x * invj + EPSF; s += d * d;
    d = av.y * invi - bv.y * invj + EPSF; s += d * d;
    d = av.z * invi - bv.z * invj + EPSF; s += d * d;
    d = av.w * invi - bv.w * invj + EPSF; s += d * d;
  }
#pragma unroll
  for (int sh = 32; sh; sh >>= 1) s += __shfl_xor(s, sh, 64);
  if (lane == 0) logd[i] = logf(sqrtf(s) + EPSF);
}

// ---------- kernel 4: deterministic fixed-order mean ----------

__global__ __launch_bounds__(256) void k_final(const float* __restrict__ logd,
                                               float* __restrict__ out) {
  __shared__ double red[256];
  double s = 0.0;
  for (int i = threadIdx.x; i < N; i += 256) s += (double)logd[i];
  red[threadIdx.x] = s;
  __syncthreads();
  for (int sh = 128; sh; sh >>= 1) {
    if ((int)threadIdx.x < sh) red[threadIdx.x] += red[threadIdx.x + sh];
    __syncthreads();
  }
  if (threadIdx.x == 0) out[0] = (float)(-red[0] / (double)N);
}

// ---------- launch ----------

extern "C" void kernel_launch(void* const* d_in, const int* in_sizes, int n_in,
                              void* d_out, int out_size, void* d_ws,
                              size_t ws_size, hipStream_t stream) {
  const float* x = (const float*)d_in[0];
  float* out = (float*)d_out;
  char* ws = (char*)d_ws;

  // ws: xq 16MB | norms 64KB | best N*8 = 128KB | logd 64KB
  signed char* xq = (signed char*)ws;
  float* norms = (float*)(ws + 16777216);
  u64* best = (u64*)(ws + 16842752);
  float* logd = (float*)(ws + 16973824);

  k_normalize<<<N / 4, 256, 0, stream>>>(x, xq, norms, best);
  k_argmax<<<NBLK, 512, LDS_TOT, stream>>>(xq, best);
  k_dist<<<N / 4, 256, 0, stream>>>(x, norms, best, logd);
  k_final<<<1, 256, 0, stream>>>(logd, out);
}